// Round 2
// baseline (834.451 us; speedup 1.0000x reference)
//
#include <hip/hip_runtime.h>
#include <hip/hip_bf16.h>

#define F_TOTAL 128
#define N_HEADS 8
#define HEAD_DIM 16

// ---------------------------------------------------------------------------
// Kernel 1: per-head linear projections q,k,v = x_h @ W_h^T  (fp32 in/out)
// Weights staged in LDS transposed as [d][f] so the inner loop is
// broadcast/conflict-free. x row staged in LDS per node.
// ---------------------------------------------------------------------------
__global__ __launch_bounds__(128) void proj_kernel(
    const float* __restrict__ x,
    const float* __restrict__ wq,
    const float* __restrict__ wk,
    const float* __restrict__ wv,
    float* __restrict__ q, float* __restrict__ k, float* __restrict__ v,
    int n_nodes)
{
    __shared__ float swq[HEAD_DIM][F_TOTAL];
    __shared__ float swk[HEAD_DIM][F_TOTAL];
    __shared__ float swv[HEAD_DIM][F_TOTAL];
    __shared__ float sx[F_TOTAL];

    const int f = threadIdx.x;          // 0..127 output feature (h*16+e)
    const int h = f >> 4;

    // global weight layout: [h][e][d] flat == [f][d]; store as s[d][f]
    for (int d = 0; d < HEAD_DIM; ++d) {
        swq[d][f] = wq[f * HEAD_DIM + d];
        swk[d][f] = wk[f * HEAD_DIM + d];
        swv[d][f] = wv[f * HEAD_DIM + d];
    }
    __syncthreads();

    for (int n = blockIdx.x; n < n_nodes; n += gridDim.x) {
        sx[f] = x[(size_t)n * F_TOTAL + f];
        __syncthreads();
        float accq = 0.f, acck = 0.f, accv = 0.f;
        #pragma unroll
        for (int d = 0; d < HEAD_DIM; ++d) {
            float xv = sx[h * HEAD_DIM + d];
            accq += xv * swq[d][f];
            acck += xv * swk[d][f];
            accv += xv * swv[d][f];
        }
        size_t o = (size_t)n * F_TOTAL + f;
        q[o] = accq;
        k[o] = acck;
        v[o] = accv;
        __syncthreads();   // protect sx before next iteration's overwrite
    }
}

// ---------------------------------------------------------------------------
// Kernel 2: per-pair attention + scatter-add directly into d_out (fp32).
// 128 threads per pair (one per feature), 2 pairs per 256-thread block.
// Head-local 16-lane reduction via xor shuffles (stays inside head groups).
// ---------------------------------------------------------------------------
#define PAIRS_PER_BLOCK 2
__global__ __launch_bounds__(256) void pair_kernel(
    const float* __restrict__ q,
    const float* __restrict__ k,
    const float* __restrict__ v,
    const float* __restrict__ w_ij,
    const int* __restrict__ idx_i,
    const int* __restrict__ idx_j,
    const float* __restrict__ phi,
    float* __restrict__ out,
    int n_pairs)
{
    const int p = blockIdx.x * PAIRS_PER_BLOCK + (threadIdx.x >> 7);
    const int f = threadIdx.x & (F_TOTAL - 1);
    if (p >= n_pairs) return;

    const int i = idx_i[p];
    const int j = idx_j[p];

    const float qv = q[(size_t)i * F_TOTAL + f];
    const float wv = w_ij[(size_t)p * F_TOTAL + f];
    const float kv = k[(size_t)j * F_TOTAL + f];
    const float vv = v[(size_t)j * F_TOTAL + f];

    float t = qv * wv * kv;
    // reduce across the 16 lanes of this head (xor masks stay in-group)
    t += __shfl_xor(t, 1);
    t += __shfl_xor(t, 2);
    t += __shfl_xor(t, 4);
    t += __shfl_xor(t, 8);

    const float alpha = t * 0.25f * phi[p];   // 1/sqrt(16) = 0.25
    atomicAdd(&out[(size_t)i * F_TOTAL + f], alpha * vv);
}

extern "C" void kernel_launch(void* const* d_in, const int* in_sizes, int n_in,
                              void* d_out, int out_size, void* d_ws, size_t ws_size,
                              hipStream_t stream)
{
    const float* x     = (const float*)d_in[0];
    const float* w_ij  = (const float*)d_in[1];
    const int*   idx_i = (const int*)d_in[2];
    const int*   idx_j = (const int*)d_in[3];
    const float* phi   = (const float*)d_in[4];
    const float* wq    = (const float*)d_in[5];
    const float* wk    = (const float*)d_in[6];
    const float* wv    = (const float*)d_in[7];

    const int n_nodes = in_sizes[0] / F_TOTAL;
    const int n_pairs = in_sizes[2];
    const size_t node_elems = (size_t)n_nodes * F_TOTAL;

    float* q = (float*)d_ws;
    float* k = q + node_elems;
    float* v = k + node_elems;

    float* out = (float*)d_out;

    // Harness poisons d_out with 0xAA before every replay — zero it ourselves.
    hipMemsetAsync(out, 0, node_elems * sizeof(float), stream);

    proj_kernel<<<1024, 128, 0, stream>>>(x, wq, wk, wv, q, k, v, n_nodes);

    const int n_pair_blocks = (n_pairs + PAIRS_PER_BLOCK - 1) / PAIRS_PER_BLOCK;
    pair_kernel<<<n_pair_blocks, 256, 0, stream>>>(q, k, v, w_ij, idx_i, idx_j,
                                                   phi, out, n_pairs);
}

// Round 3
// 829.475 us; speedup vs baseline: 1.0060x; 1.0060x over previous
//
#include <hip/hip_runtime.h>
#include <hip/hip_bf16.h>

#define F_TOTAL 128
#define N_HEADS 8
#define HEAD_DIM 16
#define SCAN_ITEMS 1024   // items per block in the node-histogram scan

// ---------------------------------------------------------------------------
// Kernel 1: per-head linear projections q,k,v = x_h @ W_h^T  (fp32 in/out).
// Shuffle-based: no LDS, no barriers. Each thread owns one output feature f
// (f = tid&127 stays constant across grid-stride because stride % 128 == 0)
// and keeps the 3x16 weight row in registers.
// ---------------------------------------------------------------------------
__global__ __launch_bounds__(256) void proj_kernel(
    const float* __restrict__ x,
    const float* __restrict__ wq,
    const float* __restrict__ wk,
    const float* __restrict__ wv,
    float* __restrict__ q, float* __restrict__ k, float* __restrict__ v,
    int n_nodes)
{
    const int gid = blockIdx.x * 256 + threadIdx.x;
    const int f = gid & (F_TOTAL - 1);

    float rq[16], rk[16], rv[16];
    const float4* wq4 = (const float4*)wq;
    const float4* wk4 = (const float4*)wk;
    const float4* wv4 = (const float4*)wv;
    #pragma unroll
    for (int d4 = 0; d4 < 4; ++d4) {
        float4 a = wq4[f * 4 + d4];
        rq[d4*4+0]=a.x; rq[d4*4+1]=a.y; rq[d4*4+2]=a.z; rq[d4*4+3]=a.w;
        float4 b = wk4[f * 4 + d4];
        rk[d4*4+0]=b.x; rk[d4*4+1]=b.y; rk[d4*4+2]=b.z; rk[d4*4+3]=b.w;
        float4 c = wv4[f * 4 + d4];
        rv[d4*4+0]=c.x; rv[d4*4+1]=c.y; rv[d4*4+2]=c.z; rv[d4*4+3]=c.w;
    }
    // lane of x[n][h*16+d] within this thread's wave: (f & 112) & 63, + d
    const int lanebase = (f & 112) & 63;

    const int total = n_nodes * F_TOTAL;
    const int stride = gridDim.x * 256;
    for (int idx = gid; idx < total; idx += stride) {
        const float xval = x[idx];
        float aq = 0.f, ak = 0.f, av = 0.f;
        #pragma unroll
        for (int d = 0; d < 16; ++d) {
            const float xv = __shfl(xval, lanebase + d);
            aq += xv * rq[d];
            ak += xv * rk[d];
            av += xv * rv[d];
        }
        q[idx] = aq; k[idx] = ak; v[idx] = av;
    }
}

// ---------------------------------------------------------------------------
// Counting sort of pair ids by idx_i: hist -> scan -> scatter
// ---------------------------------------------------------------------------
__global__ __launch_bounds__(256) void hist_kernel(
    const int* __restrict__ idx_i, int* __restrict__ hist, int n_pairs)
{
    const int p = blockIdx.x * 256 + threadIdx.x;
    if (p < n_pairs) atomicAdd(&hist[idx_i[p]], 1);
}

// block-level reduction of SCAN_ITEMS histogram entries -> blockSums[b]
__global__ __launch_bounds__(256) void scan_reduce_kernel(
    const int* __restrict__ hist, int* __restrict__ blockSums, int n)
{
    __shared__ int ls[256];
    const int t = threadIdx.x;
    const int base = blockIdx.x * SCAN_ITEMS + t * 4;
    int s = 0;
    if (base + 3 < n) {
        int4 h = *(const int4*)(hist + base);
        s = h.x + h.y + h.z + h.w;
    } else {
        for (int kk = 0; kk < 4; ++kk)
            if (base + kk < n) s += hist[base + kk];
    }
    ls[t] = s;
    __syncthreads();
    for (int off = 128; off > 0; off >>= 1) {
        if (t < off) ls[t] += ls[t + off];
        __syncthreads();
    }
    if (t == 0) blockSums[blockIdx.x] = ls[0];
}

// exclusive scan of blockSums (nblk <= 128), single block
__global__ __launch_bounds__(128) void scan_spine_kernel(
    int* __restrict__ blockSums, int nblk)
{
    __shared__ int ls[128];
    const int t = threadIdx.x;
    const int val = (t < nblk) ? blockSums[t] : 0;
    ls[t] = val;
    __syncthreads();
    for (int off = 1; off < 128; off <<= 1) {
        int add = (t >= off) ? ls[t - off] : 0;
        __syncthreads();
        ls[t] += add;
        __syncthreads();
    }
    if (t < nblk) blockSums[t] = ls[t] - val;   // exclusive
}

// recompute local exclusive scan + add spine offset -> offsets[]
__global__ __launch_bounds__(256) void scan_apply_kernel(
    const int* __restrict__ hist, const int* __restrict__ blockSums,
    int* __restrict__ offsets, int n)
{
    __shared__ int ls[256];
    const int t = threadIdx.x;
    const int base = blockIdx.x * SCAN_ITEMS + t * 4;
    int h0 = 0, h1 = 0, h2 = 0, h3 = 0;
    if (base + 3 < n) {
        int4 h = *(const int4*)(hist + base);
        h0 = h.x; h1 = h.y; h2 = h.z; h3 = h.w;
    } else {
        if (base + 0 < n) h0 = hist[base + 0];
        if (base + 1 < n) h1 = hist[base + 1];
        if (base + 2 < n) h2 = hist[base + 2];
        if (base + 3 < n) h3 = hist[base + 3];
    }
    const int tsum = h0 + h1 + h2 + h3;
    ls[t] = tsum;
    __syncthreads();
    for (int off = 1; off < 256; off <<= 1) {
        int add = (t >= off) ? ls[t - off] : 0;
        __syncthreads();
        ls[t] += add;
        __syncthreads();
    }
    int off = blockSums[blockIdx.x] + (ls[t] - tsum);   // exclusive base
    if (base + 0 < n) offsets[base + 0] = off; off += h0;
    if (base + 1 < n) offsets[base + 1] = off; off += h1;
    if (base + 2 < n) offsets[base + 2] = off; off += h2;
    if (base + 3 < n) offsets[base + 3] = off;
}

__global__ __launch_bounds__(256) void scatter_kernel(
    const int* __restrict__ idx_i, const int* __restrict__ offsets,
    int* __restrict__ cursor, int* __restrict__ perm, int n_pairs)
{
    const int p = blockIdx.x * 256 + threadIdx.x;
    if (p < n_pairs) {
        const int i = idx_i[p];
        const int pos = offsets[i] + atomicAdd(&cursor[i], 1);
        perm[pos] = p;
    }
}

// ---------------------------------------------------------------------------
// Kernel 3: segmented attention aggregation. One node per 128 threads
// (2 nodes per 256-thread block). Register accumulation, single store,
// no atomics. Nodes with zero pairs write zeros.
// ---------------------------------------------------------------------------
__global__ __launch_bounds__(256) void segment_kernel(
    const float* __restrict__ q,
    const float* __restrict__ k,
    const float* __restrict__ v,
    const float* __restrict__ w_ij,
    const int* __restrict__ idx_j,
    const float* __restrict__ phi,
    const int* __restrict__ hist,
    const int* __restrict__ offsets,
    const int* __restrict__ perm,
    float* __restrict__ out,
    int n_nodes)
{
    const int node = blockIdx.x * 2 + (threadIdx.x >> 7);
    const int f = threadIdx.x & (F_TOTAL - 1);
    if (node >= n_nodes) return;

    const int cnt = hist[node];
    const int start = offsets[node];
    const float qv = q[(size_t)node * F_TOTAL + f];

    float acc = 0.f;
    for (int c = 0; c < cnt; ++c) {
        const int p = perm[start + c];
        const int j = idx_j[p];
        const float wv = w_ij[(size_t)p * F_TOTAL + f];
        const float kv = k[(size_t)j * F_TOTAL + f];
        const float vv = v[(size_t)j * F_TOTAL + f];
        float t = qv * wv * kv;
        t += __shfl_xor(t, 1);
        t += __shfl_xor(t, 2);
        t += __shfl_xor(t, 4);
        t += __shfl_xor(t, 8);
        acc += t * 0.25f * phi[p] * vv;   // 1/sqrt(16) = 0.25
    }
    out[(size_t)node * F_TOTAL + f] = acc;
}

extern "C" void kernel_launch(void* const* d_in, const int* in_sizes, int n_in,
                              void* d_out, int out_size, void* d_ws, size_t ws_size,
                              hipStream_t stream)
{
    const float* x     = (const float*)d_in[0];
    const float* w_ij  = (const float*)d_in[1];
    const int*   idx_i = (const int*)d_in[2];
    const int*   idx_j = (const int*)d_in[3];
    const float* phi   = (const float*)d_in[4];
    const float* wq    = (const float*)d_in[5];
    const float* wk    = (const float*)d_in[6];
    const float* wv    = (const float*)d_in[7];

    const int n_nodes = in_sizes[0] / F_TOTAL;
    const int n_pairs = in_sizes[2];
    const size_t node_elems = (size_t)n_nodes * F_TOTAL;

    // workspace layout
    float* q       = (float*)d_ws;                 // node_elems
    float* k       = q + node_elems;               // node_elems
    float* v       = k + node_elems;               // node_elems
    int*   hist    = (int*)(v + node_elems);       // n_nodes
    int*   cursor  = hist + n_nodes;               // n_nodes
    int*   offsets = cursor + n_nodes;             // n_nodes
    int*   blockSums = offsets + n_nodes;          // <=128 (pad to 128)
    int*   perm    = blockSums + 128;              // n_pairs

    // zero hist + cursor in one shot (they're contiguous)
    hipMemsetAsync(hist, 0, (size_t)2 * n_nodes * sizeof(int), stream);

    proj_kernel<<<3072, 256, 0, stream>>>(x, wq, wk, wv, q, k, v, n_nodes);

    const int pair_blocks = (n_pairs + 255) / 256;
    hist_kernel<<<pair_blocks, 256, 0, stream>>>(idx_i, hist, n_pairs);

    const int nblk = (n_nodes + SCAN_ITEMS - 1) / SCAN_ITEMS;   // 98 for 100k
    scan_reduce_kernel<<<nblk, 256, 0, stream>>>(hist, blockSums, n_nodes);
    scan_spine_kernel<<<1, 128, 0, stream>>>(blockSums, nblk);
    scan_apply_kernel<<<nblk, 256, 0, stream>>>(hist, blockSums, offsets, n_nodes);

    scatter_kernel<<<pair_blocks, 256, 0, stream>>>(idx_i, offsets, cursor, perm, n_pairs);

    segment_kernel<<<(n_nodes + 1) / 2, 256, 0, stream>>>(
        q, k, v, w_ij, idx_j, phi, hist, offsets, perm, (float*)d_out, n_nodes);
}

// Round 4
// 692.537 us; speedup vs baseline: 1.2049x; 1.1977x over previous
//
#include <hip/hip_runtime.h>
#include <hip/hip_bf16.h>

#define F_TOTAL 128
#define N_HEADS 8
#define HEAD_DIM 16
#define SCAN_ITEMS 1024   // items per block in the node-histogram scan

// ---------------------------------------------------------------------------
// Kernel 1: per-head linear projections q,k,v = x_h @ W_h^T  (fp32 in/out).
// Shuffle-based: no LDS, no barriers. Each thread owns one output feature f
// (f = tid&127 stays constant across grid-stride because stride % 128 == 0)
// and keeps the 3x16 weight row in registers.
// ---------------------------------------------------------------------------
__global__ __launch_bounds__(256) void proj_kernel(
    const float* __restrict__ x,
    const float* __restrict__ wq,
    const float* __restrict__ wk,
    const float* __restrict__ wv,
    float* __restrict__ q, float* __restrict__ k, float* __restrict__ v,
    int n_nodes)
{
    const int gid = blockIdx.x * 256 + threadIdx.x;
    const int f = gid & (F_TOTAL - 1);

    float rq[16], rk[16], rv[16];
    const float4* wq4 = (const float4*)wq;
    const float4* wk4 = (const float4*)wk;
    const float4* wv4 = (const float4*)wv;
    #pragma unroll
    for (int d4 = 0; d4 < 4; ++d4) {
        float4 a = wq4[f * 4 + d4];
        rq[d4*4+0]=a.x; rq[d4*4+1]=a.y; rq[d4*4+2]=a.z; rq[d4*4+3]=a.w;
        float4 b = wk4[f * 4 + d4];
        rk[d4*4+0]=b.x; rk[d4*4+1]=b.y; rk[d4*4+2]=b.z; rk[d4*4+3]=b.w;
        float4 c = wv4[f * 4 + d4];
        rv[d4*4+0]=c.x; rv[d4*4+1]=c.y; rv[d4*4+2]=c.z; rv[d4*4+3]=c.w;
    }
    // lane holding x[n][h*16+d] within this thread's wave
    const int lanebase = (f & 112) & 63;

    const int total = n_nodes * F_TOTAL;
    const int stride = gridDim.x * 256;
    for (int idx = gid; idx < total; idx += stride) {
        const float xval = __builtin_nontemporal_load(x + idx);  // read-once
        float aq = 0.f, ak = 0.f, av = 0.f;
        #pragma unroll
        for (int d = 0; d < 16; ++d) {
            const float xv = __shfl(xval, lanebase + d);
            aq += xv * rq[d];
            ak += xv * rk[d];
            av += xv * rv[d];
        }
        q[idx] = aq; k[idx] = ak; v[idx] = av;
    }
}

// ---------------------------------------------------------------------------
// Counting sort of pairs by idx_i: hist -> scan -> scatter (emits sorted
// j/phi/p arrays so the hot kernel has no perm->idx_j indirection).
// ---------------------------------------------------------------------------
__global__ __launch_bounds__(256) void hist_kernel(
    const int* __restrict__ idx_i, int* __restrict__ hist, int n_pairs)
{
    const int p = blockIdx.x * 256 + threadIdx.x;
    if (p < n_pairs) atomicAdd(&hist[idx_i[p]], 1);
}

__global__ __launch_bounds__(256) void scan_reduce_kernel(
    const int* __restrict__ hist, int* __restrict__ blockSums, int n)
{
    __shared__ int ls[256];
    const int t = threadIdx.x;
    const int base = blockIdx.x * SCAN_ITEMS + t * 4;
    int s = 0;
    if (base + 3 < n) {
        int4 h = *(const int4*)(hist + base);
        s = h.x + h.y + h.z + h.w;
    } else {
        for (int kk = 0; kk < 4; ++kk)
            if (base + kk < n) s += hist[base + kk];
    }
    ls[t] = s;
    __syncthreads();
    for (int off = 128; off > 0; off >>= 1) {
        if (t < off) ls[t] += ls[t + off];
        __syncthreads();
    }
    if (t == 0) blockSums[blockIdx.x] = ls[0];
}

__global__ __launch_bounds__(128) void scan_spine_kernel(
    int* __restrict__ blockSums, int nblk)
{
    __shared__ int ls[128];
    const int t = threadIdx.x;
    const int val = (t < nblk) ? blockSums[t] : 0;
    ls[t] = val;
    __syncthreads();
    for (int off = 1; off < 128; off <<= 1) {
        int add = (t >= off) ? ls[t - off] : 0;
        __syncthreads();
        ls[t] += add;
        __syncthreads();
    }
    if (t < nblk) blockSums[t] = ls[t] - val;   // exclusive
}

__global__ __launch_bounds__(256) void scan_apply_kernel(
    const int* __restrict__ hist, const int* __restrict__ blockSums,
    int* __restrict__ offsets, int n)
{
    __shared__ int ls[256];
    const int t = threadIdx.x;
    const int base = blockIdx.x * SCAN_ITEMS + t * 4;
    int h0 = 0, h1 = 0, h2 = 0, h3 = 0;
    if (base + 3 < n) {
        int4 h = *(const int4*)(hist + base);
        h0 = h.x; h1 = h.y; h2 = h.z; h3 = h.w;
    } else {
        if (base + 0 < n) h0 = hist[base + 0];
        if (base + 1 < n) h1 = hist[base + 1];
        if (base + 2 < n) h2 = hist[base + 2];
        if (base + 3 < n) h3 = hist[base + 3];
    }
    const int tsum = h0 + h1 + h2 + h3;
    ls[t] = tsum;
    __syncthreads();
    for (int off = 1; off < 256; off <<= 1) {
        int add = (t >= off) ? ls[t - off] : 0;
        __syncthreads();
        ls[t] += add;
        __syncthreads();
    }
    int off = blockSums[blockIdx.x] + (ls[t] - tsum);   // exclusive base
    if (base + 0 < n) offsets[base + 0] = off; off += h0;
    if (base + 1 < n) offsets[base + 1] = off; off += h1;
    if (base + 2 < n) offsets[base + 2] = off; off += h2;
    if (base + 3 < n) offsets[base + 3] = off;
}

__global__ __launch_bounds__(256) void scatter_kernel(
    const int* __restrict__ idx_i, const int* __restrict__ idx_j,
    const float* __restrict__ phi, const int* __restrict__ offsets,
    int* __restrict__ cursor,
    int* __restrict__ p_s, int* __restrict__ j_s, float* __restrict__ phi_s,
    int n_pairs)
{
    const int p = blockIdx.x * 256 + threadIdx.x;
    if (p < n_pairs) {
        const int i = idx_i[p];
        const int pos = offsets[i] + atomicAdd(&cursor[i], 1);
        p_s[pos]   = p;
        j_s[pos]   = idx_j[p];
        phi_s[pos] = phi[p];
    }
}

// ---------------------------------------------------------------------------
// Kernel 3: segmented attention aggregation. One node per 128 threads
// (2 nodes per 256-thread block). 4-pair unroll: 12 independent 512B loads
// in flight per iteration. w_ij read nontemporally (stream-once) so the
// L3-resident k/v working set isn't evicted. No atomics, single store.
// ---------------------------------------------------------------------------
__global__ __launch_bounds__(256) void segment_kernel(
    const float* __restrict__ q,
    const float* __restrict__ k,
    const float* __restrict__ v,
    const float* __restrict__ w_ij,
    const int* __restrict__ hist,
    const int* __restrict__ offsets,
    const int* __restrict__ p_s,
    const int* __restrict__ j_s,
    const float* __restrict__ phi_s,
    float* __restrict__ out,
    int n_nodes)
{
    const int node = blockIdx.x * 2 + (threadIdx.x >> 7);
    const int f = threadIdx.x & (F_TOTAL - 1);
    if (node >= n_nodes) return;

    const int cnt = hist[node];
    const int start = offsets[node];
    const float qv = q[(size_t)node * F_TOTAL + f];

    float acc = 0.f;
    int c = 0;
    for (; c + 4 <= cnt; c += 4) {
        const int b = start + c;
        const int p0 = p_s[b+0], p1 = p_s[b+1], p2 = p_s[b+2], p3 = p_s[b+3];
        const int j0 = j_s[b+0], j1 = j_s[b+1], j2 = j_s[b+2], j3 = j_s[b+3];
        const float ph0 = phi_s[b+0], ph1 = phi_s[b+1],
                    ph2 = phi_s[b+2], ph3 = phi_s[b+3];

        const float w0 = __builtin_nontemporal_load(w_ij + (size_t)p0 * F_TOTAL + f);
        const float w1 = __builtin_nontemporal_load(w_ij + (size_t)p1 * F_TOTAL + f);
        const float w2 = __builtin_nontemporal_load(w_ij + (size_t)p2 * F_TOTAL + f);
        const float w3 = __builtin_nontemporal_load(w_ij + (size_t)p3 * F_TOTAL + f);
        const float k0 = k[(size_t)j0 * F_TOTAL + f];
        const float k1 = k[(size_t)j1 * F_TOTAL + f];
        const float k2 = k[(size_t)j2 * F_TOTAL + f];
        const float k3 = k[(size_t)j3 * F_TOTAL + f];
        const float v0 = v[(size_t)j0 * F_TOTAL + f];
        const float v1 = v[(size_t)j1 * F_TOTAL + f];
        const float v2 = v[(size_t)j2 * F_TOTAL + f];
        const float v3 = v[(size_t)j3 * F_TOTAL + f];

        float t0 = qv * w0 * k0;
        float t1 = qv * w1 * k1;
        float t2 = qv * w2 * k2;
        float t3 = qv * w3 * k3;
        #pragma unroll
        for (int m = 1; m < 16; m <<= 1) {
            t0 += __shfl_xor(t0, m);
            t1 += __shfl_xor(t1, m);
            t2 += __shfl_xor(t2, m);
            t3 += __shfl_xor(t3, m);
        }
        acc += t0 * 0.25f * ph0 * v0;
        acc += t1 * 0.25f * ph1 * v1;
        acc += t2 * 0.25f * ph2 * v2;
        acc += t3 * 0.25f * ph3 * v3;
    }
    for (; c < cnt; ++c) {
        const int b = start + c;
        const int p = p_s[b];
        const int j = j_s[b];
        const float ph = phi_s[b];
        const float wv = __builtin_nontemporal_load(w_ij + (size_t)p * F_TOTAL + f);
        const float kv = k[(size_t)j * F_TOTAL + f];
        const float vv = v[(size_t)j * F_TOTAL + f];
        float t = qv * wv * kv;
        #pragma unroll
        for (int m = 1; m < 16; m <<= 1) t += __shfl_xor(t, m);
        acc += t * 0.25f * ph * vv;
    }
    __builtin_nontemporal_store(acc, out + (size_t)node * F_TOTAL + f);
}

extern "C" void kernel_launch(void* const* d_in, const int* in_sizes, int n_in,
                              void* d_out, int out_size, void* d_ws, size_t ws_size,
                              hipStream_t stream)
{
    const float* x     = (const float*)d_in[0];
    const float* w_ij  = (const float*)d_in[1];
    const int*   idx_i = (const int*)d_in[2];
    const int*   idx_j = (const int*)d_in[3];
    const float* phi   = (const float*)d_in[4];
    const float* wq    = (const float*)d_in[5];
    const float* wk    = (const float*)d_in[6];
    const float* wv    = (const float*)d_in[7];

    const int n_nodes = in_sizes[0] / F_TOTAL;
    const int n_pairs = in_sizes[2];
    const size_t node_elems = (size_t)n_nodes * F_TOTAL;

    // workspace layout
    float* q         = (float*)d_ws;               // node_elems
    float* k         = q + node_elems;             // node_elems
    float* v         = k + node_elems;             // node_elems
    int*   hist      = (int*)(v + node_elems);     // n_nodes
    int*   cursor    = hist + n_nodes;             // n_nodes
    int*   offsets   = cursor + n_nodes;           // n_nodes
    int*   blockSums = offsets + n_nodes;          // <=128 (pad to 128)
    int*   p_s       = blockSums + 128;            // n_pairs
    int*   j_s       = p_s + n_pairs;              // n_pairs
    float* phi_s     = (float*)(j_s + n_pairs);    // n_pairs

    // zero hist + cursor in one shot (they're contiguous)
    hipMemsetAsync(hist, 0, (size_t)2 * n_nodes * sizeof(int), stream);

    proj_kernel<<<3072, 256, 0, stream>>>(x, wq, wk, wv, q, k, v, n_nodes);

    const int pair_blocks = (n_pairs + 255) / 256;
    hist_kernel<<<pair_blocks, 256, 0, stream>>>(idx_i, hist, n_pairs);

    const int nblk = (n_nodes + SCAN_ITEMS - 1) / SCAN_ITEMS;   // 98 for 100k
    scan_reduce_kernel<<<nblk, 256, 0, stream>>>(hist, blockSums, n_nodes);
    scan_spine_kernel<<<1, 128, 0, stream>>>(blockSums, nblk);
    scan_apply_kernel<<<nblk, 256, 0, stream>>>(hist, blockSums, offsets, n_nodes);

    scatter_kernel<<<pair_blocks, 256, 0, stream>>>(
        idx_i, idx_j, phi, offsets, cursor, p_s, j_s, phi_s, n_pairs);

    segment_kernel<<<(n_nodes + 1) / 2, 256, 0, stream>>>(
        q, k, v, w_ij, hist, offsets, p_s, j_s, phi_s, (float*)d_out, n_nodes);
}